// Round 5
// baseline (289.486 us; speedup 1.0000x reference)
//
#include <hip/hip_runtime.h>
#include <hip/hip_bf16.h>
#include <cstdint>
#include <cstddef>

// Problem constants (from reference)
#define N_NODES 20000
#define N_EDGES 320000
#define IN_DIM  256
#define HID     128     // layer0 per-head feat
#define OUT_DIM 64      // layer1 feat
#define H0      4       // layer0 heads

static __device__ __forceinline__ float leaky(float x) { return x > 0.f ? x : 0.2f * x; }

// ---------------- CSR build ----------------
__global__ void zero_i32(int* __restrict__ p, int n) {
  int i = blockIdx.x * 256 + threadIdx.x;
  if (i < n) p[i] = 0;
}

__global__ void hist_kernel(const int* __restrict__ dst, int* __restrict__ cnt) {
  int e = blockIdx.x * 256 + threadIdx.x;
  if (e < N_EDGES) atomicAdd(&cnt[dst[e]], 1);
}

// single-block scan, 1024 threads, 20 elems/thread, 2 barriers total.
#define SCAN_PER 20
__global__ __launch_bounds__(1024) void scan_kernel(const int* __restrict__ cnt,
                                                    int* __restrict__ rowstart) {
  int t = threadIdx.x;
  int lane = t & 63, wid = t >> 6;
  int base = t * SCAN_PER;
  int loc[SCAN_PER];
  int s = 0;
  if (t < N_NODES / SCAN_PER) {
#pragma unroll
    for (int k = 0; k < SCAN_PER; k++) { loc[k] = cnt[base + k]; s += loc[k]; }
  }
  int v = s;
#pragma unroll
  for (int off = 1; off < 64; off <<= 1) {
    int u = __shfl_up(v, off);
    if (lane >= off) v += u;
  }
  __shared__ int wsum[16];
  if (lane == 63) wsum[wid] = v;
  __syncthreads();
  if (t == 0) {
    int a = 0;
#pragma unroll
    for (int i = 0; i < 16; i++) { int x = wsum[i]; wsum[i] = a; a += x; }
    rowstart[N_NODES] = a;
  }
  __syncthreads();
  int excl = wsum[wid] + (v - s);
  if (t < N_NODES / SCAN_PER) {
    int a = excl;
#pragma unroll
    for (int k = 0; k < SCAN_PER; k++) { rowstart[base + k] = a; a += loc[k]; }
  }
}

__global__ void fill_kernel(const int* __restrict__ src, const int* __restrict__ dst,
                            const int* __restrict__ rowstart, int* __restrict__ fill,
                            int* __restrict__ csr_src, int* __restrict__ csr_dst) {
  int e = blockIdx.x * 256 + threadIdx.x;
  if (e < N_EDGES) {
    int d = dst[e];
    int p = atomicAdd(&fill[d], 1);
    csr_src[rowstart[d] + p] = src[e];
    csr_dst[rowstart[d] + p] = d;
  }
}

// ---------------- fp32 -> bf16 hi/lo pre-split (one float4 per thread) ------
using short8  = __attribute__((ext_vector_type(8))) short;
using short4v = __attribute__((ext_vector_type(4))) short;
using f32x4   = __attribute__((ext_vector_type(4))) float;

struct HL { short h; short l; };
static __device__ __forceinline__ HL split_bf16(float x) {
  HL r;
  __hip_bfloat16 hb = __float2bfloat16(x);
  float hf = __bfloat162float(hb);
  __hip_bfloat16 lb = __float2bfloat16(x - hf);
  r.h = *(short*)&hb;
  r.l = *(short*)&lb;
  return r;
}

__global__ void presplit_kernel(const float* __restrict__ in, short* __restrict__ oh,
                                short* __restrict__ ol, int n4) {
  int i = blockIdx.x * 256 + threadIdx.x;
  if (i >= n4) return;
  int base = i * 4;
  float4 v = *(const float4*)&in[base];
  HL e0 = split_bf16(v.x), e1 = split_bf16(v.y), e2 = split_bf16(v.z), e3 = split_bf16(v.w);
  short4v hv, lv;
  hv[0] = e0.h; hv[1] = e1.h; hv[2] = e2.h; hv[3] = e3.h;
  lv[0] = e0.l; lv[1] = e1.l; lv[2] = e2.l; lv[3] = e3.l;
  *(short4v*)&oh[base] = hv;
  *(short4v*)&ol[base] = lv;
}

// ---------------- bf16x3 MFMA GEMM with pre-split operands ----------------
// C = Ah*Bh + Ah*Bl + Al*Bh. A: [M,K] bf16 hi/lo; B: [K,N] bf16 hi/lo.
// Tile BM x BN x BK=32; 256 threads (4 waves as 2x2), 16x16x32 MFMA.
// Layouts (learn_hip m89/m120): A-frag A[m=lane&15][k=(lane>>4)*8+j];
// B-frag B[k=(lane>>4)*8+j][n=lane&15]; C/D col=lane&15, row=(lane>>4)*4+reg.

#define LDK 40   // padded LDS k-stride (32 + 8 shorts), keeps 16B alignment

template <int BM, int BN>
__global__ __launch_bounds__(256) void gemm_pre(const short* __restrict__ Ah,
                                                const short* __restrict__ Al,
                                                const short* __restrict__ Bh,
                                                const short* __restrict__ Bl,
                                                float* __restrict__ C,
                                                __hip_bfloat16* __restrict__ Cb,
                                                int M, int N, int K) {
  constexpr int MI = BM / 32;
  constexpr int NT = BN / 32;
  constexpr int TPR = 256 / BM;        // threads per A row
  constexpr int KPT = 32 / TPR;        // shorts per thread per A array
  constexpr int BNPT = BN / 8;         // B shorts per thread
  __shared__ short Ash[BM * LDK];
  __shared__ short Asl[BM * LDK];
  __shared__ short Bsh[BN * LDK];
  __shared__ short Bsl[BN * LDK];
  const int tid  = threadIdx.x;
  const int lane = tid & 63;
  const int wave = tid >> 6;
  const int wm = (wave >> 1) * (BM / 2);
  const int wn = (wave & 1) * (BN / 2);
  const int row0 = blockIdx.y * BM;
  const int col0 = blockIdx.x * BN;
  const int lr = lane & 15;
  const int lq = lane >> 4;
  const int ar = tid / TPR;
  const int ak = (tid % TPR) * KPT;
  const int bk = tid & 31;
  const int bn = (tid >> 5) * BNPT;

  f32x4 acc[MI][NT];
#pragma unroll
  for (int i = 0; i < MI; i++)
#pragma unroll
    for (int j = 0; j < NT; j++) acc[i][j] = (f32x4){0.f, 0.f, 0.f, 0.f};

  for (int k0 = 0; k0 < K; k0 += 32) {
    // --- stage A ---
    {
      const bool ok = (row0 + ar) < M;
      const size_t gofs = (size_t)(row0 + ar) * K + k0 + ak;
#pragma unroll
      for (int i = 0; i < KPT / 8; i++) {
        short8 hv = ok ? *(const short8*)&Ah[gofs + 8 * i] : (short8){0,0,0,0,0,0,0,0};
        short8 lv = ok ? *(const short8*)&Al[gofs + 8 * i] : (short8){0,0,0,0,0,0,0,0};
        *(short8*)&Ash[ar * LDK + ak + 8 * i] = hv;
        *(short8*)&Asl[ar * LDK + ak + 8 * i] = lv;
      }
    }
    // --- stage B (transpose to [n][k]) ---
    {
      const size_t gofs = (size_t)(k0 + bk) * N + col0 + bn;
#pragma unroll
      for (int i = 0; i < BNPT / 8; i++) {
        short8 hv = *(const short8*)&Bh[gofs + 8 * i];
        short8 lv = *(const short8*)&Bl[gofs + 8 * i];
#pragma unroll
        for (int j = 0; j < 8; j++) {
          Bsh[(bn + 8 * i + j) * LDK + bk] = hv[j];
          Bsl[(bn + 8 * i + j) * LDK + bk] = lv[j];
        }
      }
    }
    __syncthreads();
    short8 a_h[MI], a_l[MI], b_h[NT], b_l[NT];
#pragma unroll
    for (int mi = 0; mi < MI; mi++) {
      int r = wm + mi * 16 + lr;
      a_h[mi] = *(const short8*)&Ash[r * LDK + lq * 8];
      a_l[mi] = *(const short8*)&Asl[r * LDK + lq * 8];
    }
#pragma unroll
    for (int nj = 0; nj < NT; nj++) {
      int c = wn + nj * 16 + lr;
      b_h[nj] = *(const short8*)&Bsh[c * LDK + lq * 8];
      b_l[nj] = *(const short8*)&Bsl[c * LDK + lq * 8];
    }
#pragma unroll
    for (int mi = 0; mi < MI; mi++) {
#pragma unroll
      for (int nj = 0; nj < NT; nj++) {
        acc[mi][nj] = __builtin_amdgcn_mfma_f32_16x16x32_bf16(a_h[mi], b_l[nj], acc[mi][nj], 0, 0, 0);
        acc[mi][nj] = __builtin_amdgcn_mfma_f32_16x16x32_bf16(a_l[mi], b_h[nj], acc[mi][nj], 0, 0, 0);
        acc[mi][nj] = __builtin_amdgcn_mfma_f32_16x16x32_bf16(a_h[mi], b_h[nj], acc[mi][nj], 0, 0, 0);
      }
    }
    __syncthreads();
  }
#pragma unroll
  for (int mi = 0; mi < MI; mi++) {
#pragma unroll
    for (int r = 0; r < 4; r++) {
      int row = row0 + wm + mi * 16 + lq * 4 + r;
      if (row < M) {
#pragma unroll
        for (int nj = 0; nj < NT; nj++) {
          float val = acc[mi][nj][r];
          size_t idx = (size_t)row * N + col0 + wn + nj * 16 + lr;
          if (C)  C[idx] = val;
          if (Cb) Cb[idx] = __float2bfloat16(val);
        }
      }
    }
  }
}

// ---------------- coef (layer0, bf16 feat): el/er = sum_d feat*a ----------------
__global__ void coef0_kernel(const __hip_bfloat16* __restrict__ feat,
                             const float* __restrict__ al, const float* __restrict__ ar,
                             float* __restrict__ el, float* __restrict__ er) {
  int w = blockIdx.x * 4 + (threadIdx.x >> 6);
  int lane = threadIdx.x & 63;
  if (w >= N_NODES * H0) return;
  int n = w / H0, h = w % H0;
  int d0 = 2 * lane;
  __hip_bfloat162 f2 = *(const __hip_bfloat162*)&feat[(size_t)n * (H0 * HID) + h * HID + d0];
  float2 a2 = *(const float2*)&al[h * HID + d0];
  float2 r2 = *(const float2*)&ar[h * HID + d0];
  float fx = __bfloat162float(f2.x), fy = __bfloat162float(f2.y);
  float sl = fx * a2.x + fy * a2.y;
  float sr = fx * r2.x + fy * r2.y;
  for (int off = 32; off; off >>= 1) {
    sl += __shfl_xor(sl, off);
    sr += __shfl_xor(sr, off);
  }
  if (lane == 0) { el[w] = sl; er[w] = sr; }
}

// ---------------- coef (layer1, fp32 feat, D=64, H=1) ----------------
__global__ void coef1_kernel(const float* __restrict__ feat, const float* __restrict__ al,
                             const float* __restrict__ ar, float* __restrict__ el,
                             float* __restrict__ er) {
  int w = blockIdx.x * 4 + (threadIdx.x >> 6);
  int lane = threadIdx.x & 63;
  if (w >= N_NODES) return;
  float fv = feat[(size_t)w * OUT_DIM + lane];
  float sl = fv * al[lane];
  float sr = fv * ar[lane];
  for (int off = 32; off; off >>= 1) {
    sl += __shfl_xor(sl, off);
    sr += __shfl_xor(sr, off);
  }
  if (lane == 0) { el[w] = sl; er[w] = sr; }
}

// ---------------- edge scores in CSR order ----------------
// layer0: e_csr[pos*4+h] = leaky(el[src*4+h] + er[dst*4+h])
__global__ void edge0_kernel(const int* __restrict__ csr_src, const int* __restrict__ csr_dst,
                             const float* __restrict__ el, const float* __restrict__ er,
                             float* __restrict__ e_csr) {
  int p = blockIdx.x * 256 + threadIdx.x;
  if (p >= N_EDGES) return;
  int s = csr_src[p], d = csr_dst[p];
  float4 l = *(const float4*)&el[s * 4];
  float4 r = *(const float4*)&er[d * 4];
  float4 o;
  o.x = leaky(l.x + r.x); o.y = leaky(l.y + r.y);
  o.z = leaky(l.z + r.z); o.w = leaky(l.w + r.w);
  *(float4*)&e_csr[(size_t)p * 4] = o;
}

// layer1: e_csr2[pos] = leaky(el[src] + er[dst])
__global__ void edge1_kernel(const int* __restrict__ csr_src, const int* __restrict__ csr_dst,
                             const float* __restrict__ el, const float* __restrict__ er,
                             float* __restrict__ e_csr) {
  int p = blockIdx.x * 256 + threadIdx.x;
  if (p >= N_EDGES) return;
  e_csr[p] = leaky(el[csr_src[p]] + er[csr_dst[p]]);
}

// ---------------- in-place edge softmax normalize (per dst node) ----------------
// layer0: wave per node; lane i handles (edge i>>2, head i&3); contiguous reads.
__global__ __launch_bounds__(256) void norm0_kernel(const int* __restrict__ rowstart,
                                                    float* __restrict__ e_csr) {
  int n = blockIdx.x * 4 + (threadIdx.x >> 6);
  int lane = threadIdx.x & 63;
  if (n >= N_NODES) return;
  int start = rowstart[n];
  int cnt4 = (rowstart[n + 1] - start) * 4;
  if (cnt4 == 0) return;
  float* base = e_csr + (size_t)start * 4;
  float m = -1e30f;
  for (int i0 = 0; i0 < cnt4; i0 += 64) {
    int i = i0 + lane;
    m = fmaxf(m, (i < cnt4) ? base[i] : -1e30f);
  }
#pragma unroll
  for (int off = 4; off < 64; off <<= 1) m = fmaxf(m, __shfl_xor(m, off));  // same h = lane&3
  float ssum = 0.f;
  for (int i0 = 0; i0 < cnt4; i0 += 64) {
    int i = i0 + lane;
    ssum += (i < cnt4) ? __expf(base[i] - m) : 0.f;
  }
#pragma unroll
  for (int off = 4; off < 64; off <<= 1) ssum += __shfl_xor(ssum, off);
  float inv = 1.f / ssum;
  for (int i0 = 0; i0 < cnt4; i0 += 64) {
    int i = i0 + lane;
    if (i < cnt4) base[i] = __expf(base[i] - m) * inv;
  }
}

// layer1: wave per node; lane = edge index.
__global__ __launch_bounds__(256) void norm1_kernel(const int* __restrict__ rowstart,
                                                    float* __restrict__ e_csr) {
  int n = blockIdx.x * 4 + (threadIdx.x >> 6);
  int lane = threadIdx.x & 63;
  if (n >= N_NODES) return;
  int start = rowstart[n];
  int deg = rowstart[n + 1] - start;
  if (deg == 0) return;
  float* base = e_csr + start;
  float m = -1e30f;
  for (int i0 = 0; i0 < deg; i0 += 64) {
    int i = i0 + lane;
    m = fmaxf(m, (i < deg) ? base[i] : -1e30f);
  }
#pragma unroll
  for (int off = 1; off < 64; off <<= 1) m = fmaxf(m, __shfl_xor(m, off));
  float ssum = 0.f;
  for (int i0 = 0; i0 < deg; i0 += 64) {
    int i = i0 + lane;
    ssum += (i < deg) ? __expf(base[i] - m) : 0.f;
  }
#pragma unroll
  for (int off = 1; off < 64; off <<= 1) ssum += __shfl_xor(ssum, off);
  float inv = 1.f / ssum;
  for (int i0 = 0; i0 < deg; i0 += 64) {
    int i = i0 + lane;
    if (i < deg) base[i] = __expf(base[i] - m) * inv;
  }
}

// ---------------- layer0 aggregation: per node, 4 waves = 4 heads ----------------
// alpha precomputed in e_csr; feat gathered bf16; h1 written as bf16 hi/lo split.
__global__ __launch_bounds__(256) void agg0_kernel(const int* __restrict__ rowstart,
                                                   const int* __restrict__ csr_src,
                                                   const float* __restrict__ alpha,
                                                   const __hip_bfloat16* __restrict__ featb,
                                                   const float* __restrict__ bias,
                                                   short* __restrict__ h1h,
                                                   short* __restrict__ h1l) {
  int n = blockIdx.x;
  int h = threadIdx.x >> 6;
  int lane = threadIdx.x & 63;
  int start = rowstart[n];
  int deg = rowstart[n + 1] - start;
  float accx = 0.f, accy = 0.f;
#pragma unroll 4
  for (int i = 0; i < deg; i++) {
    int pos = start + i;
    float a = alpha[(size_t)pos * 4 + h];       // wave-uniform broadcast
    int s = csr_src[pos];                       // wave-uniform broadcast
    __hip_bfloat162 f = *(const __hip_bfloat162*)&featb[(size_t)s * (H0 * HID) + h * HID + 2 * lane];
    accx += a * __bfloat162float(f.x);
    accy += a * __bfloat162float(f.y);
  }
  int d0 = 2 * lane;
  float o0 = accx + bias[h * HID + d0];
  float o1 = accy + bias[h * HID + d0 + 1];
  o0 = o0 > 0.f ? o0 : (__expf(o0) - 1.f);   // ELU
  o1 = o1 > 0.f ? o1 : (__expf(o1) - 1.f);
  size_t idx = (size_t)n * (H0 * HID) + h * HID + d0;
  HL s0 = split_bf16(o0), s1 = split_bf16(o1);
  short4v dummy;
  (void)dummy;
  h1h[idx] = s0.h; h1h[idx + 1] = s1.h;
  h1l[idx] = s0.l; h1l[idx + 1] = s1.l;
}

// ---------------- layer1 aggregation: one wave per node, D=64, fp32 ----------------
__global__ __launch_bounds__(64) void agg1_kernel(const int* __restrict__ rowstart,
                                                  const int* __restrict__ csr_src,
                                                  const float* __restrict__ alpha,
                                                  const float* __restrict__ feat,
                                                  const float* __restrict__ bias,
                                                  float* __restrict__ out) {
  int n = blockIdx.x;
  int lane = threadIdx.x;
  int start = rowstart[n];
  int deg = rowstart[n + 1] - start;
  float acc = 0.f;
#pragma unroll 4
  for (int i = 0; i < deg; i++) {
    int pos = start + i;
    float a = alpha[pos];
    int s = csr_src[pos];
    acc += a * feat[(size_t)s * OUT_DIM + lane];
  }
  out[(size_t)n * OUT_DIM + lane] = acc + bias[lane];
}

extern "C" void kernel_launch(void* const* d_in, const int* in_sizes, int n_in,
                              void* d_out, int out_size, void* d_ws, size_t ws_size,
                              hipStream_t stream) {
  const float* x   = (const float*)d_in[0];
  const int*   src = (const int*)d_in[1];
  const int*   dst = (const int*)d_in[2];
  const float* W1  = (const float*)d_in[3];
  const float* al1 = (const float*)d_in[4];
  const float* ar1 = (const float*)d_in[5];
  const float* b1  = (const float*)d_in[6];
  const float* W2  = (const float*)d_in[7];
  const float* al2 = (const float*)d_in[8];
  const float* ar2 = (const float*)d_in[9];
  const float* b2  = (const float*)d_in[10];

  char* ws = (char*)d_ws;
  size_t off = 0;
  auto alloc = [&](size_t bytes) -> void* {
    void* p = ws + off;
    off += (bytes + 255) & ~(size_t)255;
    return p;
  };
  int* cnt      = (int*)alloc((size_t)2 * N_NODES * 4);  // cnt + fill contiguous
  int* fill     = cnt + N_NODES;
  int* rowstart = (int*)alloc((size_t)(N_NODES + 1) * 4);
  int* csr_src  = (int*)alloc((size_t)N_EDGES * 4);
  int* csr_dst  = (int*)alloc((size_t)N_EDGES * 4);
  short* xh     = (short*)alloc((size_t)N_NODES * IN_DIM * 2);
  short* xl     = (short*)alloc((size_t)N_NODES * IN_DIM * 2);
  short* W1h    = (short*)alloc((size_t)IN_DIM * (H0 * HID) * 2);
  short* W1l    = (short*)alloc((size_t)IN_DIM * (H0 * HID) * 2);
  short* W2h    = (short*)alloc((size_t)(H0 * HID) * OUT_DIM * 2);
  short* W2l    = (short*)alloc((size_t)(H0 * HID) * OUT_DIM * 2);
  __hip_bfloat16* feat1b = (__hip_bfloat16*)alloc((size_t)N_NODES * (H0 * HID) * 2);
  float* el1    = (float*)alloc((size_t)N_NODES * H0 * 4);
  float* er1    = (float*)alloc((size_t)N_NODES * H0 * 4);
  float* e_csr  = (float*)alloc((size_t)N_EDGES * H0 * 4);
  short* h1h    = (short*)alloc((size_t)N_NODES * (H0 * HID) * 2);
  short* h1l    = (short*)alloc((size_t)N_NODES * (H0 * HID) * 2);
  float* feat2  = (float*)alloc((size_t)N_NODES * OUT_DIM * 4);
  float* el2    = (float*)alloc((size_t)N_NODES * 4);
  float* er2    = (float*)alloc((size_t)N_NODES * 4);
  float* e_csr2 = (float*)alloc((size_t)N_EDGES * 4);
  (void)ws_size; (void)in_sizes; (void)n_in; (void)out_size;

  // 1) CSR build (shared by both layers)
  zero_i32<<<(2 * N_NODES + 255) / 256, 256, 0, stream>>>(cnt, 2 * N_NODES);
  hist_kernel<<<(N_EDGES + 255) / 256, 256, 0, stream>>>(dst, cnt);
  scan_kernel<<<1, 1024, 0, stream>>>(cnt, rowstart);
  fill_kernel<<<(N_EDGES + 255) / 256, 256, 0, stream>>>(src, dst, rowstart, fill, csr_src, csr_dst);

  // 2) pre-split GEMM operands
  presplit_kernel<<<(N_NODES * IN_DIM / 4 + 255) / 256, 256, 0, stream>>>(x, xh, xl, N_NODES * IN_DIM / 4);
  presplit_kernel<<<(IN_DIM * H0 * HID / 4 + 255) / 256, 256, 0, stream>>>(W1, W1h, W1l, IN_DIM * H0 * HID / 4);
  presplit_kernel<<<(H0 * HID * OUT_DIM / 4 + 255) / 256, 256, 0, stream>>>(W2, W2h, W2l, H0 * HID * OUT_DIM / 4);

  // 3) layer 0: GEMM -> bf16 feat, coef, edge-softmax, aggregate (-> bf16 hi/lo h1)
  {
    dim3 g((H0 * HID) / 128, (N_NODES + 127) / 128);
    gemm_pre<128, 128><<<g, 256, 0, stream>>>(xh, xl, W1h, W1l, (float*)nullptr, feat1b,
                                              N_NODES, H0 * HID, IN_DIM);
  }
  coef0_kernel<<<(N_NODES * H0 + 3) / 4, 256, 0, stream>>>(feat1b, al1, ar1, el1, er1);
  edge0_kernel<<<(N_EDGES + 255) / 256, 256, 0, stream>>>(csr_src, csr_dst, el1, er1, e_csr);
  norm0_kernel<<<(N_NODES + 3) / 4, 256, 0, stream>>>(rowstart, e_csr);
  agg0_kernel<<<N_NODES, 256, 0, stream>>>(rowstart, csr_src, e_csr, feat1b, b1, h1h, h1l);

  // 4) layer 1
  {
    dim3 g(OUT_DIM / 64, (N_NODES + 63) / 64);
    gemm_pre<64, 64><<<g, 256, 0, stream>>>(h1h, h1l, W2h, W2l, feat2, (__hip_bfloat16*)nullptr,
                                            N_NODES, OUT_DIM, H0 * HID);
  }
  coef1_kernel<<<(N_NODES + 3) / 4, 256, 0, stream>>>(feat2, al2, ar2, el2, er2);
  edge1_kernel<<<(N_EDGES + 255) / 256, 256, 0, stream>>>(csr_src, csr_dst, el2, er2, e_csr2);
  norm1_kernel<<<(N_NODES + 3) / 4, 256, 0, stream>>>(rowstart, e_csr2);
  agg1_kernel<<<N_NODES, 64, 0, stream>>>(rowstart, csr_src, e_csr2, feat2, b2, (float*)d_out);
}